// Round 1
// baseline (5642.530 us; speedup 1.0000x reference)
//
#include <hip/hip_runtime.h>
#include <stdint.h>

typedef __attribute__((ext_vector_type(8))) __bf16 bf16x8;
typedef __attribute__((ext_vector_type(4))) float f32x4;

#define DEVI static __device__ __forceinline__

DEVI bf16x8 bzero8(){ bf16x8 r;
#pragma unroll
  for (int i=0;i<8;++i) r[i]=(__bf16)0.0f; return r; }

DEVI bf16x8 ld8(const __bf16* p){ return *(const bf16x8*)p; }
DEVI void st8(__bf16* p, bf16x8 v){ *(bf16x8*)p = v; }

DEVI f32x4 MFMA(bf16x8 a, bf16x8 b, f32x4 c){
  return __builtin_amdgcn_mfma_f32_16x16x32_bf16(a, b, c, 0, 0, 0);
}

DEVI float sigf(float x){ return 1.0f/(1.0f+__expf(-x)); }

// device-scope grid barrier (monotonic counter, one slot per barrier group)
DEVI void gridbar(unsigned* ctr, unsigned target){
  __syncthreads();
  if (threadIdx.x == 0){
    __threadfence();
    __hip_atomic_fetch_add(ctr, 1u, __ATOMIC_RELEASE, __HIP_MEMORY_SCOPE_AGENT);
    while (__hip_atomic_load(ctr, __ATOMIC_ACQUIRE, __HIP_MEMORY_SCOPE_AGENT) < target)
      __builtin_amdgcn_s_sleep(2);
    __threadfence();
  }
  __syncthreads();
}

// ---------------- packing ----------------
// packed-B layout: group g = (kt*NT + nt)*64 + lane ; elems g*8..g*8+7 =
// W[nt*16 + (lane&15)][kt*32 + (lane>>4)*8 + j]   (zero outside Nsrc/Kreal)
DEVI void packGroup(const float* W, int Nsrc, int Kreal, int NT, __bf16* dst, long g){
  int kt = (int)(g / (NT*64));
  int rem = (int)(g % (NT*64));
  int nt = rem >> 6, ln = rem & 63;
  int row = nt*16 + (ln & 15);
  int col = kt*32 + ((ln >> 4) << 3);
  bf16x8 v = bzero8();
  if (row < Nsrc){
#pragma unroll
    for (int j=0;j<8;++j){ int c = col + j; if (c < Kreal) v[j] = (__bf16)W[(long)row*Kreal + c]; }
  }
  st8(dst + g*8, v);
}

DEVI void packGroupCat(const float* Wih, const float* Whh, __bf16* dst, long g){
  // N=2048, K=544 (32 from Wih then 512 from Whh), NT=128
  int kt = (int)(g / (128*64));
  int rem = (int)(g % (128*64));
  int nt = rem >> 6, ln = rem & 63;
  int row = nt*16 + (ln & 15);
  int col = kt*32 + ((ln >> 4) << 3);
  bf16x8 v;
  if (col < 32){
#pragma unroll
    for (int j=0;j<8;++j) v[j] = (__bf16)Wih[(long)row*32 + col + j];
  } else {
#pragma unroll
    for (int j=0;j<8;++j) v[j] = (__bf16)Whh[(long)row*512 + (col-32) + j];
  }
  st8(dst + g*8, v);
}

__global__ void zeroBarK(unsigned* p){ p[threadIdx.x] = 0u; }

__global__ void packSmallK(const float* __restrict__ xs, const float* __restrict__ eWih,
    const float* __restrict__ eWhh, const float* __restrict__ ebih, const float* __restrict__ ebhh,
    const float* __restrict__ attnW, const float* __restrict__ combW,
    __bf16* __restrict__ xsb, __bf16* __restrict__ wcatp, float* __restrict__ biasc,
    __bf16* __restrict__ attnp, __bf16* __restrict__ combp)
{
  long g = (long)blockIdx.x*blockDim.x + threadIdx.x;
  const long nWcat = 17L*128*64;   // 139264
  const long nXs   = 92160;        // 737280/8
  const long nBias = 2048;
  const long nAttn = 33L*2*64;     // 4224
  const long nComb = 33L*32*64;    // 67584
  if (g < nWcat){ packGroupCat(eWih, eWhh, wcatp, g); return; }
  g -= nWcat;
  if (g < nXs){
    const float* s = xs + g*8; bf16x8 v;
#pragma unroll
    for (int j=0;j<8;++j) v[j] = (__bf16)s[j];
    st8(xsb + g*8, v); return;
  }
  g -= nXs;
  if (g < nBias){ biasc[g] = ebih[g] + ebhh[g]; return; }
  g -= nBias;
  if (g < nAttn){ packGroup(attnW, 30, 1032, 2, attnp, g); return; }
  g -= nAttn;
  if (g < nComb){ packGroup(combW, 512, 1032, 32, combp, g); return; }
}

__global__ void packPencK(const float* __restrict__ Wf, const float* __restrict__ Wb,
    const float* __restrict__ bihf, const float* __restrict__ bhhf,
    const float* __restrict__ bihb, const float* __restrict__ bhhb,
    __bf16* __restrict__ pf, __bf16* __restrict__ pb, float* __restrict__ bsum)
{
  long g = (long)blockIdx.x*blockDim.x + threadIdx.x;
  const long nW = 64L*128*64;   // 524288 per dir
  if (g < nW){ packGroup(Wf, 2048, 2048, 128, pf, g); return; }
  g -= nW;
  if (g < nW){ packGroup(Wb, 2048, 2048, 128, pb, g); return; }
  g -= nW;
  if (g < 2048){ bsum[g] = bihf[g] + bhhf[g]; return; }
  g -= 2048;
  if (g < 2048){ bsum[2048+g] = bihb[g] + bhhb[g]; return; }
}

// ---------------- encoder step (fused GEMM + LSTM cell + scatter) ----------------
// block: 16 rows x 2048 gate-cols, 4 waves (wave w = gate w, cols w*512..+512)
__global__ __launch_bounds__(256, 1) void encStepK(
    const __bf16* __restrict__ xsb,      // [12][1920][32]
    __bf16* __restrict__ henc,           // [1920][512]
    float* __restrict__ cenc,            // [1920][512]
    const __bf16* __restrict__ wcatp,
    const float* __restrict__ biasc,     // [2048]
    const int* __restrict__ xlen,
    __bf16* __restrict__ ctx,            // [1920][1024]  (h|c)
    int t)
{
  __shared__ float glds[4][16][128];
  const int tid = threadIdx.x;
  const int w = tid >> 6, ln = tid & 63;
  const int m0 = blockIdx.x * 16;
  f32x4 acc[32];
#pragma unroll
  for (int i=0;i<32;++i) acc[i] = (f32x4){0.f,0.f,0.f,0.f};

  const int arow = m0 + (ln & 15);
  const int kc = (ln >> 4) << 3;
  const int ktEnd = (t == 0) ? 1 : 17;
  for (int kt = 0; kt < ktEnd; ++kt){
    bf16x8 a;
    if (kt == 0) a = ld8(xsb + ((long)t*1920 + arow)*32 + kc);
    else         a = ld8(henc + (long)arow*512 + (kt-1)*32 + kc);
    const __bf16* bp = wcatp + (((long)kt*128 + w*32)*64 + ln)*8;
#pragma unroll
    for (int n2 = 0; n2 < 32; ++n2){
      bf16x8 b = ld8(bp + (long)n2*512);
      acc[n2] = MFMA(a, b, acc[n2]);
    }
  }
  const int r4 = (ln >> 4) << 2;
#pragma unroll
  for (int ck = 0; ck < 4; ++ck){
    __syncthreads();
#pragma unroll
    for (int q = 0; q < 8; ++q){
      int c = q*16 + (ln & 15);
#pragma unroll
      for (int r = 0; r < 4; ++r) glds[w][r4 + r][c] = acc[ck*8 + q][r];
    }
    __syncthreads();
    for (int it = 0; it < 8; ++it){
      int idx = tid + it*256;
      int rr = idx >> 7, hcl = idx & 127;
      int hcg = ck*128 + hcl;
      int n = m0 + rr;
      float ig = glds[0][rr][hcl] + biasc[hcg];
      float fg = glds[1][rr][hcl] + biasc[512 + hcg];
      float gg = glds[2][rr][hcl] + biasc[1024 + hcg];
      float og = glds[3][rr][hcl] + biasc[1536 + hcg];
      float c_old = (t == 0) ? 0.0f : cenc[(long)n*512 + hcg];
      float cn = sigf(fg)*c_old + sigf(ig)*tanhf(gg);
      float h  = sigf(og)*tanhf(cn);
      cenc[(long)n*512 + hcg] = cn;
      henc[(long)n*512 + hcg] = (__bf16)h;
      if (xlen[n] - 1 == t){
        ctx[(long)n*1024 + hcg]       = (__bf16)h;
        ctx[(long)n*1024 + 512 + hcg] = (__bf16)cn;
      }
    }
  }
}

// ---------------- pyramid input GEMM (xp = in @ Wih^T + bsum), both dirs ----------------
__global__ __launch_bounds__(1024) void pencInK(
   const __bf16* __restrict__ inb,   // [M][2048]
   const __bf16* __restrict__ wpf, const __bf16* __restrict__ wpb,
   const float* __restrict__ bsum,   // [2][2048]
   float* __restrict__ xpf, float* __restrict__ xpb,
   int M)
{
  const int tid = threadIdx.x, ln = tid & 63, wv = tid >> 6;
  const int rg = wv >> 2, cg = wv & 3;
  const int dir = blockIdx.z;
  const int m0 = blockIdx.x*64 + rg*16;
  const int nb = blockIdx.y;
  const __bf16* wp = dir ? wpb : wpf;
  float* xp = dir ? xpb : xpf;
  const float* bs = bsum + dir*2048;
  f32x4 acc[4];
#pragma unroll
  for (int i=0;i<4;++i) acc[i] = (f32x4){0.f,0.f,0.f,0.f};
  const int arow = m0 + (ln & 15);
  const int kc = (ln >> 4) << 3;
  const bool aok = arow < M;
  for (int kt = 0; kt < 64; ++kt){
    bf16x8 a = aok ? ld8(inb + (long)arow*2048 + kt*32 + kc) : bzero8();
    const __bf16* bp = wp + (((long)kt*128 + nb*16 + cg*4)*64 + ln)*8;
#pragma unroll
    for (int q = 0; q < 4; ++q){
      bf16x8 b = ld8(bp + (long)q*512);
      acc[q] = MFMA(a, b, acc[q]);
    }
  }
  const int r4 = (ln >> 4) << 2;
#pragma unroll
  for (int q = 0; q < 4; ++q){
    int col = (nb*16 + cg*4 + q)*16 + (ln & 15);
#pragma unroll
    for (int r = 0; r < 4; ++r){
      int rowo = m0 + r4 + r;
      if (rowo < M) xp[(long)rowo*2048 + col] = acc[q][r] + bs[col];
    }
  }
}

// ---------------- pyramid recurrence: persistent, weight-stationary ----------------
// 32 blocks: [0..15]=fwd, [16..31]=bwd; each owns 32 hidden cols (128 gate rows in LDS)
__global__ __launch_bounds__(256, 1) void pyrRecK(
  const float* __restrict__ WhhF, const float* __restrict__ WhhB,   // [2048][512]
  const float* __restrict__ xpf, const float* __restrict__ xpb,     // [4T][2048]
  __bf16* __restrict__ hbuf,        // [2dir][2par][4][512]
  __bf16* __restrict__ outb,        // layers 0-2: [4][T][1024] bf16
  float* __restrict__ outf,         // layer 3: enc_out f32
  float* __restrict__ h0f, __bf16* __restrict__ h0b,
  unsigned* __restrict__ ctrBase,   // two counters 64B apart
  int T, int isLast)
{
  __shared__ __align__(16) __bf16 WL[128*512];
  __shared__ float glds[4][4][32];
  const int tid = threadIdx.x, ln = tid & 63, w = tid >> 6;
  const int bk = blockIdx.x;
  const int dir = bk >> 4, blk = bk & 15;
  const int hc0 = blk * 32;
  const float* Whh = dir ? WhhB : WhhF;
  const float* xp  = dir ? xpb : xpf;
  unsigned* ctr = (unsigned*)((char*)ctrBase + dir*64);

  // preload 128x512 weight slice -> LDS (bf16, XOR swizzled)
  for (int it = 0; it < 32; ++it){
    int g = it*256 + tid;
    int rho = g >> 6, c8 = g & 63;
    int gate = rho >> 5, hcl = rho & 31;
    const float* src = Whh + ((long)(gate*512 + hc0 + hcl))*512 + c8*8;
    bf16x8 v;
#pragma unroll
    for (int j=0;j<8;++j) v[j] = (__bf16)src[j];
    int off = (rho*1024 + c8*16) ^ ((rho & 7) << 4);
    st8((__bf16*)((char*)WL + off), v);
  }
  if (tid < 128){
    int b = tid >> 5, hcl = tid & 31;
    hbuf[((dir*2 + 0)*4 + b)*512 + hc0 + hcl] = (__bf16)0.0f;
  }
  unsigned ph = 1;
  gridbar(ctr, 16u*ph); ph++;

  float cv = 0.0f;
  const int arow = ln & 15;
  const int kc = (ln >> 4) << 3;
  for (int t = 0; t < T; ++t){
    int par = t & 1;
    int pos = dir ? (T-1-t) : t;
    const __bf16* hsrc = hbuf + ((dir*2 + par)*4)*512;
    f32x4 a0 = {0.f,0.f,0.f,0.f}, a1 = {0.f,0.f,0.f,0.f};
    const int rho0 = w*32 + (ln & 15);
    const int rho1 = rho0 + 16;
    for (int kt = 0; kt < 16; ++kt){
      bf16x8 a = (arow < 4) ? ld8(hsrc + arow*512 + kt*32 + kc) : bzero8();
      int k2 = (kt*32 + kc)*2;
      bf16x8 b0 = ld8((__bf16*)((char*)WL + ((rho0*1024 + k2) ^ ((rho0 & 7) << 4))));
      bf16x8 b1 = ld8((__bf16*)((char*)WL + ((rho1*1024 + k2) ^ ((rho1 & 7) << 4))));
      a0 = MFMA(a, b0, a0);
      a1 = MFMA(a, b1, a1);
    }
    if (ln < 16){
#pragma unroll
      for (int r=0;r<4;++r){ glds[w][r][ln] = a0[r]; glds[w][r][16+ln] = a1[r]; }
    }
    __syncthreads();
    if (tid < 128){
      int b = tid >> 5, hcl = tid & 31, hcg = hc0 + hcl;
      const float* xr = xp + ((long)(b*T + pos))*2048;
      float ig = glds[0][b][hcl] + xr[hcg];
      float fg = glds[1][b][hcl] + xr[512 + hcg];
      float gg = glds[2][b][hcl] + xr[1024 + hcg];
      float og = glds[3][b][hcl] + xr[1536 + hcg];
      cv = sigf(fg)*cv + sigf(ig)*tanhf(gg);
      float h = sigf(og)*tanhf(cv);
      hbuf[((dir*2 + (par^1))*4 + b)*512 + hcg] = (__bf16)h;
      if (!isLast){
        outb[((long)(b*T + pos))*1024 + dir*512 + hcg] = (__bf16)h;
      } else {
        outf[((long)(b*T + pos))*1024 + dir*512 + hcg] = h;
        if (t == T-1){
          h0f[b*1024 + dir*512 + hcg] = h;
          h0b[b*1024 + dir*512 + hcg] = (__bf16)h;
        }
      }
    }
    gridbar(ctr, 16u*ph); ph++;
  }
}

// ---------------- decoder: persistent, 64 blocks (16 hidden cols each) ----------------
__global__ __launch_bounds__(256, 1) void decoderK(
  const float* __restrict__ gWih,  // [3072][512]
  const float* __restrict__ gWhh,  // [3072][1024]
  const float* __restrict__ gbih, const float* __restrict__ gbhh,
  const float* __restrict__ combBias, const float* __restrict__ attnBias,
  const float* __restrict__ outW, const float* __restrict__ outBias,
  const __bf16* __restrict__ attnP, const __bf16* __restrict__ combP,
  const float* __restrict__ encOut,  // [4][30][1024]
  float* __restrict__ hf,            // [2][4][1024]
  __bf16* __restrict__ hb,           // [2][4][1024]
  __bf16* __restrict__ xbf,          // [4][512]
  float* __restrict__ dout,          // [128][8]
  unsigned* __restrict__ ctr)
{
  __shared__ __align__(16) __bf16 WgiL[48*512];
  __shared__ __align__(16) __bf16 WghL[48*1024];
  __shared__ __align__(16) __bf16 ctxvL[4*1040];
  __shared__ __align__(16) __bf16 inpL[32];
  __shared__ float awL[4][30];
  __shared__ float redL[4][8];
  __shared__ float ghL[3][4][16];
  __shared__ float rzL[2][4][16];
  __shared__ float inL[4][16], hnL[4][16];

  const int tid = threadIdx.x, ln = tid & 63, w = tid >> 6;
  const int bk = blockIdx.x;
  const int hc0 = bk * 16;

  // preload GRU weight slices -> LDS bf16 swizzled
  for (int it = 0; it < 12; ++it){
    int g = it*256 + tid;
    int rho = g >> 6, c8 = g & 63;
    int gate = rho >> 4, r16 = rho & 15;
    const float* s = gWih + ((long)(gate*1024 + hc0 + r16))*512 + c8*8;
    bf16x8 v;
#pragma unroll
    for (int j=0;j<8;++j) v[j] = (__bf16)s[j];
    st8((__bf16*)((char*)WgiL + ((rho*1024 + c8*16) ^ ((rho & 7) << 4))), v);
  }
  for (int it = 0; it < 24; ++it){
    int g = it*256 + tid;
    int rho = g >> 7, c8 = g & 127;
    int gate = rho >> 4, r16 = rho & 15;
    const float* s = gWhh + ((long)(gate*1024 + hc0 + r16))*1024 + c8*8;
    bf16x8 v;
#pragma unroll
    for (int j=0;j<8;++j) v[j] = (__bf16)s[j];
    st8((__bf16*)((char*)WghL + ((rho*2048 + c8*16) ^ ((rho & 7) << 4))), v);
  }
  __syncthreads();

  unsigned ph = 1;
  for (int s = 0; s <= 32; ++s){
    if (s > 0){ gridbar(ctr, 64u*ph); ph++; }
    int par = s & 1;
    if (s == 0){
      if (tid < 32) inpL[tid] = (__bf16)0.0f;
      __syncthreads();
    } else {
      // logits = h @ outW^T + outBias ; log_softmax -> inp, dout
      int o = tid >> 3, sl = tid & 7;
      int b = o >> 3, l = o & 7;
      const float* hrow = hf + (par*4 + b)*1024;
      const float* wrow = outW + l*1024;
      float p = 0.f;
      for (int k = sl*128; k < sl*128 + 128; ++k) p += hrow[k]*wrow[k];
      p += __shfl_down(p, 4);
      p += __shfl_down(p, 2);
      p += __shfl_down(p, 1);
      if (sl == 0) redL[b][l] = p + outBias[l];
      __syncthreads();
      if (tid < 4){
        float m = redL[tid][0];
        for (int l2=1;l2<8;++l2) m = fmaxf(m, redL[tid][l2]);
        float sum = 0.f;
        for (int l2=0;l2<8;++l2) sum += __expf(redL[tid][l2]-m);
        float lse = m + __logf(sum);
        for (int l2=0;l2<8;++l2){
          float lp = redL[tid][l2] - lse;
          inpL[tid*8 + l2] = (__bf16)lp;
          if (bk == 0) dout[((long)tid*32 + (s-1))*8 + l2] = lp;
        }
      }
      __syncthreads();
    }
    if (s == 32) break;

    const __bf16* hbp = hb + (par*4)*1024;
    // attention logits (waves 0,1)
    if (w < 2){
      f32x4 acc = {0.f,0.f,0.f,0.f};
      for (int kt = 0; kt < 33; ++kt){
        int k = kt*32 + ((ln >> 4) << 3);
        int row = ln & 15;
        bf16x8 a;
        if (row >= 4) a = bzero8();
        else if (k == 0) a = ld8(inpL + row*8);
        else { int off = k - 8; a = (off < 1024) ? ld8(hbp + row*1024 + off) : bzero8(); }
        bf16x8 b = ld8(attnP + (((long)kt*2 + w)*64 + ln)*8);
        acc = MFMA(a, b, acc);
      }
      if (ln < 16){
        int col = w*16 + ln;
        if (col < 30){
#pragma unroll
          for (int r=0;r<4;++r) awL[r][col] = acc[r] + attnBias[col];
        }
      }
    }
    __syncthreads();
    if (tid < 4){
      float m = awL[tid][0];
      for (int t2=1;t2<30;++t2) m = fmaxf(m, awL[tid][t2]);
      float sum = 0.f;
      for (int t2=0;t2<30;++t2){ float e = __expf(awL[tid][t2]-m); awL[tid][t2] = e; sum += e; }
      float inv = 1.0f/sum;
      for (int t2=0;t2<30;++t2) awL[tid][t2] *= inv;
    }
    __syncthreads();
    // ctxv (redundant per block)
    for (int it = 0; it < 16; ++it){
      int idx = tid + it*256;
      int b = idx >> 10, d = idx & 1023;
      float sum = 0.f;
      for (int t2=0;t2<30;++t2) sum += awL[b][t2]*encOut[((long)b*30 + t2)*1024 + d];
      ctxvL[b*1040 + d] = (__bf16)sum;
    }
    __syncthreads();
    // comb slice (wave 0 of blocks < 32)  || gh gates (waves 1-3)
    if (w == 0){
      if (bk < 32){
        f32x4 acc = {0.f,0.f,0.f,0.f};
        for (int kt = 0; kt < 33; ++kt){
          int k = kt*32 + ((ln >> 4) << 3);
          int row = ln & 15;
          bf16x8 a;
          if (row >= 4) a = bzero8();
          else if (k == 0) a = ld8(inpL + row*8);
          else { int off = k - 8; a = (off < 1024) ? ld8(ctxvL + row*1040 + off) : bzero8(); }
          bf16x8 b = ld8(combP + (((long)kt*32 + bk)*64 + ln)*8);
          acc = MFMA(a, b, acc);
        }
        if (ln < 16){
          int col = bk*16 + ln;
#pragma unroll
          for (int r=0;r<4;++r){
            float x = acc[r] + combBias[col];
            xbf[r*512 + col] = (__bf16)fmaxf(x, 0.0f);
          }
        }
      }
    } else {
      int gate = w - 1;
      f32x4 acc = {0.f,0.f,0.f,0.f};
      for (int kt = 0; kt < 32; ++kt){
        int row = ln & 15;
        int k = kt*32 + ((ln >> 4) << 3);
        bf16x8 a = (row < 4) ? ld8(hbp + row*1024 + k) : bzero8();
        int rho = gate*16 + row;
        bf16x8 b = ld8((__bf16*)((char*)WghL + ((rho*2048 + k*2) ^ ((rho & 7) << 4))));
        acc = MFMA(a, b, acc);
      }
      if (ln < 16){
#pragma unroll
        for (int r=0;r<4;++r) ghL[gate][r][ln] = acc[r];
      }
    }
    gridbar(ctr, 64u*ph); ph++;
    // gi gates + gate math (waves 0-2)
    if (w < 3){
      int gate = w;
      f32x4 acc = {0.f,0.f,0.f,0.f};
      for (int kt = 0; kt < 16; ++kt){
        int row = ln & 15;
        int k = kt*32 + ((ln >> 4) << 3);
        bf16x8 a = (row < 4) ? ld8(xbf + row*512 + k) : bzero8();
        int rho = gate*16 + row;
        bf16x8 b = ld8((__bf16*)((char*)WgiL + ((rho*1024 + k*2) ^ ((rho & 7) << 4))));
        acc = MFMA(a, b, acc);
      }
      if (ln < 16){
        int hcg = hc0 + ln;
        float bi = gbih[gate*1024 + hcg];
        float bh = gbhh[gate*1024 + hcg];
#pragma unroll
        for (int r=0;r<4;++r){
          float gi_v = acc[r] + bi;
          float gh_v = ghL[gate][r][ln] + bh;
          if (gate == 0) rzL[0][r][ln] = sigf(gi_v + gh_v);
          else if (gate == 1) rzL[1][r][ln] = sigf(gi_v + gh_v);
          else { inL[r][ln] = gi_v; hnL[r][ln] = gh_v; }
        }
      }
    }
    __syncthreads();
    if (tid < 64){
      int b = tid >> 4, l = tid & 15;
      int hcg = hc0 + l;
      float n = tanhf(inL[b][l] + rzL[0][b][l]*hnL[b][l]);
      float z = rzL[1][b][l];
      float hold = hf[(par*4 + b)*1024 + hcg];
      float hnew = (1.0f - z)*n + z*hold;
      hf[((par^1)*4 + b)*1024 + hcg] = hnew;
      hb[((par^1)*4 + b)*1024 + hcg] = (__bf16)hnew;
    }
  }
}

// ---------------- host ----------------
// ws layout (bytes)
static const size_t O_BAR   = 0;
static const size_t O_XSB   = 1024;
static const size_t O_WCATP = 1475584;
static const size_t O_BIASC = 3703808;
static const size_t O_HENC  = 3712000;
static const size_t O_CENC  = 5678080;
static const size_t O_CTX   = 9610240;
static const size_t O_WIHPF = 13542400;
static const size_t O_WIHPB = 21931008;
static const size_t O_BSUM  = 30319616;
static const size_t O_XPF   = 30336000;
static const size_t O_XPB   = 38200320;
static const size_t O_HPYR  = 46064640;
static const size_t O_OUTA  = 46081024;
static const size_t O_OUTB  = 48047104;
static const size_t O_ENCO  = 49030144;
static const size_t O_H0F   = 49521664;
static const size_t O_H0B   = 49554432;
static const size_t O_ATTNP = 49570816;
static const size_t O_COMBP = 49638400;
static const size_t O_XBF   = 50719744;
// total 50723840 (~48.4 MiB)

extern "C" void kernel_launch(void* const* d_in, const int* in_sizes, int n_in,
                              void* d_out, int out_size, void* d_ws, size_t ws_size,
                              hipStream_t stream)
{
  const float* xs    = (const float*)d_in[0];
  const int*   xlen  = (const int*)d_in[1];
  const float* eWih  = (const float*)d_in[2];
  const float* eWhh  = (const float*)d_in[3];
  const float* ebih  = (const float*)d_in[4];
  const float* ebhh  = (const float*)d_in[5];
  const float* pWihF = (const float*)d_in[6];
  const float* pWhhF = (const float*)d_in[7];
  const float* pbihF = (const float*)d_in[8];
  const float* pbhhF = (const float*)d_in[9];
  const float* pWihB = (const float*)d_in[10];
  const float* pWhhB = (const float*)d_in[11];
  const float* pbihB = (const float*)d_in[12];
  const float* pbhhB = (const float*)d_in[13];
  const float* attnW = (const float*)d_in[14];
  const float* attnb = (const float*)d_in[15];
  const float* combW = (const float*)d_in[16];
  const float* combb = (const float*)d_in[17];
  const float* gWih  = (const float*)d_in[18];
  const float* gWhh  = (const float*)d_in[19];
  const float* gbih  = (const float*)d_in[20];
  const float* gbhh  = (const float*)d_in[21];
  const float* outW  = (const float*)d_in[22];
  const float* outb  = (const float*)d_in[23];

  char* ws = (char*)d_ws;
  unsigned* BAR   = (unsigned*)(ws + O_BAR);
  __bf16* XSB     = (__bf16*)(ws + O_XSB);
  __bf16* WCATP   = (__bf16*)(ws + O_WCATP);
  float*  BIASC   = (float*)(ws + O_BIASC);
  __bf16* HENC    = (__bf16*)(ws + O_HENC);
  float*  CENC    = (float*)(ws + O_CENC);
  __bf16* CTX     = (__bf16*)(ws + O_CTX);
  __bf16* WIHPF   = (__bf16*)(ws + O_WIHPF);
  __bf16* WIHPB   = (__bf16*)(ws + O_WIHPB);
  float*  BSUM    = (float*)(ws + O_BSUM);
  float*  XPF     = (float*)(ws + O_XPF);
  float*  XPB     = (float*)(ws + O_XPB);
  __bf16* HPYR    = (__bf16*)(ws + O_HPYR);
  __bf16* OUTA    = (__bf16*)(ws + O_OUTA);
  __bf16* OUTB    = (__bf16*)(ws + O_OUTB);
  float*  ENCO    = (float*)(ws + O_ENCO);
  float*  H0F     = (float*)(ws + O_H0F);
  __bf16* H0B     = (__bf16*)(ws + O_H0B);
  __bf16* ATTNP   = (__bf16*)(ws + O_ATTNP);
  __bf16* COMBP   = (__bf16*)(ws + O_COMBP);
  __bf16* XBF     = (__bf16*)(ws + O_XBF);

  zeroBarK<<<1, 256, 0, stream>>>(BAR);
  packSmallK<<<1193, 256, 0, stream>>>(xs, eWih, eWhh, ebih, ebhh, attnW, combW,
      XSB, WCATP, BIASC, ATTNP, COMBP);

  for (int t = 0; t < 12; ++t)
    encStepK<<<120, 256, 0, stream>>>(XSB, HENC, CENC, WCATP, BIASC, xlen, CTX, t);

  const int Ts[4] = {240, 120, 60, 30};
  const __bf16* ins[4] = {CTX, OUTA, OUTB, OUTA};
  __bf16* outs[4] = {OUTA, OUTB, OUTA, OUTB};
  for (int L = 0; L < 4; ++L){
    int T = Ts[L];
    packPencK<<<4113, 256, 0, stream>>>(pWihF + (long)L*2048*2048, pWihB + (long)L*2048*2048,
        pbihF + L*2048, pbhhF + L*2048, pbihB + L*2048, pbhhB + L*2048,
        WIHPF, WIHPB, BSUM);
    int MB = (4*T + 63)/64;
    pencInK<<<dim3(MB, 8, 2), 1024, 0, stream>>>(ins[L], WIHPF, WIHPB, BSUM, XPF, XPB, 4*T);
    pyrRecK<<<32, 256, 0, stream>>>(pWhhF + (long)L*2048*512, pWhhB + (long)L*2048*512,
        XPF, XPB, HPYR, outs[L], ENCO, H0F, H0B,
        (unsigned*)(ws + O_BAR + (size_t)L*128), T, (L==3) ? 1 : 0);
  }

  decoderK<<<64, 256, 0, stream>>>(gWih, gWhh, gbih, gbhh, combb, attnb, outW, outb,
      ATTNP, COMBP, ENCO, H0F, H0B, XBF, (float*)d_out,
      (unsigned*)(ws + O_BAR + 512));
}

// Round 2
// 3162.035 us; speedup vs baseline: 1.7845x; 1.7845x over previous
//
#include <hip/hip_runtime.h>
#include <stdint.h>

typedef __attribute__((ext_vector_type(8))) __bf16 bf16x8;
typedef __attribute__((ext_vector_type(4))) float f32x4;

#define DEVI static __device__ __forceinline__

DEVI bf16x8 bzero8(){ bf16x8 r;
#pragma unroll
  for (int i=0;i<8;++i) r[i]=(__bf16)0.0f; return r; }

DEVI bf16x8 ld8(const __bf16* p){ return *(const bf16x8*)p; }
DEVI void st8(__bf16* p, bf16x8 v){ *(bf16x8*)p = v; }

DEVI f32x4 MFMA(bf16x8 a, bf16x8 b, f32x4 c){
  return __builtin_amdgcn_mfma_f32_16x16x32_bf16(a, b, c, 0, 0, 0);
}

DEVI float sigf(float x){ return 1.0f/(1.0f+__expf(-x)); }

// ---- coherent (cross-XCD) relaxed atomics: bypass L2, NO fences ----
DEVI unsigned ald(const unsigned* p){ return __hip_atomic_load(p, __ATOMIC_RELAXED, __HIP_MEMORY_SCOPE_AGENT); }
DEVI void ast(unsigned* p, unsigned v){ __hip_atomic_store(p, v, __ATOMIC_RELAXED, __HIP_MEMORY_SCOPE_AGENT); }
DEVI float aldf(const float* p){ return __hip_atomic_load(p, __ATOMIC_RELAXED, __HIP_MEMORY_SCOPE_AGENT); }
DEVI void astf(float* p, float v){ __hip_atomic_store(p, v, __ATOMIC_RELAXED, __HIP_MEMORY_SCOPE_AGENT); }

DEVI bf16x8 ald8(const __bf16* p){
  const unsigned* q = (const unsigned*)p;
  union { bf16x8 v; unsigned u[4]; } r;
  r.u[0]=ald(q+0); r.u[1]=ald(q+1); r.u[2]=ald(q+2); r.u[3]=ald(q+3);
  return r.v;
}
DEVI unsigned packbf(float a, float b){
  union { __bf16 h[2]; unsigned u; } x; x.h[0]=(__bf16)a; x.h[1]=(__bf16)b; return x.u;
}
DEVI float bflo(unsigned u){ return __builtin_bit_cast(float, u<<16); }
DEVI float bfhi(unsigned u){ return __builtin_bit_cast(float, u & 0xffff0000u); }

// ---- flag barrier: per-block epoch slots (64B apart), wave-parallel poll ----
// payload stores are relaxed-agent (write-through); __syncthreads drains vmcnt
// before the flag store, so no release/acquire fences (no buffer_inv/wbl2).
DEVI void flagbar(unsigned* slots, int nblk, int bk, unsigned ep){
  __syncthreads();
  asm volatile("" ::: "memory");
  if (threadIdx.x == 0) ast(slots + (size_t)bk*16, ep);
  if ((int)threadIdx.x < nblk){
    const unsigned* sp = slots + (size_t)threadIdx.x*16;
    while (ald(sp) < ep) __builtin_amdgcn_s_sleep(1);
  }
  asm volatile("" ::: "memory");
  __syncthreads();
}

// ---------------- packing ----------------
DEVI void packGroup(const float* W, int Nsrc, int Kreal, int NT, __bf16* dst, long g){
  int kt = (int)(g / (NT*64));
  int rem = (int)(g % (NT*64));
  int nt = rem >> 6, ln = rem & 63;
  int row = nt*16 + (ln & 15);
  int col = kt*32 + ((ln >> 4) << 3);
  bf16x8 v = bzero8();
  if (row < Nsrc){
#pragma unroll
    for (int j=0;j<8;++j){ int c = col + j; if (c < Kreal) v[j] = (__bf16)W[(long)row*Kreal + c]; }
  }
  st8(dst + g*8, v);
}

// encoder wcat: gate-INTERLEAVED packed rows: packed row p <-> src row (p&3)*512 + (p>>2)
DEVI void packGroupCat(const float* Wih, const float* Whh, __bf16* dst, long g){
  int kt = (int)(g / (128*64));
  int rem = (int)(g % (128*64));
  int nt = rem >> 6, ln = rem & 63;
  int prow = nt*16 + (ln & 15);
  int src = (prow & 3)*512 + (prow >> 2);
  int col = kt*32 + ((ln >> 4) << 3);
  bf16x8 v;
  if (col < 32){
#pragma unroll
    for (int j=0;j<8;++j) v[j] = (__bf16)Wih[(long)src*32 + col + j];
  } else {
#pragma unroll
    for (int j=0;j<8;++j) v[j] = (__bf16)Whh[(long)src*512 + (col-32) + j];
  }
  st8(dst + g*8, v);
}

__global__ void zeroBarK(unsigned* p){
#pragma unroll
  for (int i=0;i<12;++i) p[i*256 + threadIdx.x] = 0u;
}

__global__ void packSmallK(const float* __restrict__ xs, const float* __restrict__ eWih,
    const float* __restrict__ eWhh, const float* __restrict__ ebih, const float* __restrict__ ebhh,
    const float* __restrict__ attnW, const float* __restrict__ combW,
    __bf16* __restrict__ xsb, __bf16* __restrict__ wcatp, float* __restrict__ biasc,
    __bf16* __restrict__ attnp, __bf16* __restrict__ combp)
{
  long g = (long)blockIdx.x*blockDim.x + threadIdx.x;
  const long nWcat = 17L*128*64;
  const long nXs   = 92160;
  const long nBias = 2048;
  const long nAttn = 33L*2*64;
  const long nComb = 33L*32*64;
  if (g < nWcat){ packGroupCat(eWih, eWhh, wcatp, g); return; }
  g -= nWcat;
  if (g < nXs){
    const float* s = xs + g*8; bf16x8 v;
#pragma unroll
    for (int j=0;j<8;++j) v[j] = (__bf16)s[j];
    st8(xsb + g*8, v); return;
  }
  g -= nXs;
  if (g < nBias){ int src = ((int)g & 3)*512 + ((int)g >> 2); biasc[g] = ebih[src] + ebhh[src]; return; }
  g -= nBias;
  if (g < nAttn){ packGroup(attnW, 30, 1032, 2, attnp, g); return; }
  g -= nAttn;
  if (g < nComb){ packGroup(combW, 512, 1032, 32, combp, g); return; }
}

__global__ void packPencK(const float* __restrict__ Wf, const float* __restrict__ Wb,
    const float* __restrict__ bihf, const float* __restrict__ bhhf,
    const float* __restrict__ bihb, const float* __restrict__ bhhb,
    __bf16* __restrict__ pf, __bf16* __restrict__ pb, float* __restrict__ bsum)
{
  long g = (long)blockIdx.x*blockDim.x + threadIdx.x;
  const long nW = 64L*128*64;
  if (g < nW){ packGroup(Wf, 2048, 2048, 128, pf, g); return; }
  g -= nW;
  if (g < nW){ packGroup(Wb, 2048, 2048, 128, pb, g); return; }
  g -= nW;
  if (g < 2048){ bsum[g] = bihf[g] + bhhf[g]; return; }
  g -= 2048;
  if (g < 2048){ bsum[2048+g] = bihb[g] + bhhb[g]; return; }
}

// ---------------- encoder step: 64 rows x 64 h-cols per block ----------------
__global__ __launch_bounds__(256, 1) void encStepK(
    const __bf16* __restrict__ xsb,      // [12][1920][32]
    __bf16* __restrict__ henc,           // [1920][512]
    float* __restrict__ cenc,            // [1920][512]
    const __bf16* __restrict__ wcatp,    // gate-interleaved packed
    const float* __restrict__ biasc,     // [2048] packed order
    const int* __restrict__ xlen,
    __bf16* __restrict__ ctx,            // [1920][1024]  (h|c)
    int t)
{
  __shared__ float glds[64][260];
  const int tid = threadIdx.x;
  const int w = tid >> 6, ln = tid & 63;
  const int m0 = blockIdx.x * 64;
  const int nb = blockIdx.y;           // 64 h-cols: [nb*64, +64)
  f32x4 acc[16];
#pragma unroll
  for (int i=0;i<16;++i) acc[i] = (f32x4){0.f,0.f,0.f,0.f};

  const int arow = m0 + w*16 + (ln & 15);
  const int kc = (ln >> 4) << 3;
  const int ktEnd = (t == 0) ? 1 : 17;
  for (int kt = 0; kt < ktEnd; ++kt){
    bf16x8 a;
    if (kt == 0) a = ld8(xsb + ((long)t*1920 + arow)*32 + kc);
    else         a = ld8(henc + (long)arow*512 + (kt-1)*32 + kc);
    const __bf16* bp = wcatp + (((long)kt*128 + nb*16)*64 + ln)*8;
#pragma unroll
    for (int n2 = 0; n2 < 16; ++n2){
      bf16x8 b = ld8(bp + (long)n2*512);
      acc[n2] = MFMA(a, b, acc[n2]);
    }
  }
  const int r4 = (ln >> 4) << 2;
#pragma unroll
  for (int n2 = 0; n2 < 16; ++n2){
#pragma unroll
    for (int r = 0; r < 4; ++r)
      glds[w*16 + r4 + r][n2*16 + (ln & 15)] = acc[n2][r];
  }
  __syncthreads();
  for (int it = 0; it < 16; ++it){
    int idx = tid + it*256;
    int mrow = idx >> 6, hcl = idx & 63;
    int n = m0 + mrow;
    int hcg = nb*64 + hcl;
    float ig = glds[mrow][hcl*4+0] + biasc[nb*256 + hcl*4+0];
    float fg = glds[mrow][hcl*4+1] + biasc[nb*256 + hcl*4+1];
    float gg = glds[mrow][hcl*4+2] + biasc[nb*256 + hcl*4+2];
    float og = glds[mrow][hcl*4+3] + biasc[nb*256 + hcl*4+3];
    float c_old = (t == 0) ? 0.0f : cenc[(long)n*512 + hcg];
    float cn = sigf(fg)*c_old + sigf(ig)*tanhf(gg);
    float h  = sigf(og)*tanhf(cn);
    cenc[(long)n*512 + hcg] = cn;
    henc[(long)n*512 + hcg] = (__bf16)h;
    if (xlen[n] - 1 == t){
      ctx[(long)n*1024 + hcg]       = (__bf16)h;
      ctx[(long)n*1024 + 512 + hcg] = (__bf16)cn;
    }
  }
}

// ---------------- pyramid input GEMM ----------------
__global__ __launch_bounds__(1024) void pencInK(
   const __bf16* __restrict__ inb,
   const __bf16* __restrict__ wpf, const __bf16* __restrict__ wpb,
   const float* __restrict__ bsum,
   float* __restrict__ xpf, float* __restrict__ xpb,
   int M)
{
  const int tid = threadIdx.x, ln = tid & 63, wv = tid >> 6;
  const int rg = wv >> 2, cg = wv & 3;
  const int dir = blockIdx.z;
  const int m0 = blockIdx.x*64 + rg*16;
  const int nb = blockIdx.y;
  const __bf16* wp = dir ? wpb : wpf;
  float* xp = dir ? xpb : xpf;
  const float* bs = bsum + dir*2048;
  f32x4 acc[4];
#pragma unroll
  for (int i=0;i<4;++i) acc[i] = (f32x4){0.f,0.f,0.f,0.f};
  const int arow = m0 + (ln & 15);
  const int kc = (ln >> 4) << 3;
  const bool aok = arow < M;
  for (int kt = 0; kt < 64; ++kt){
    bf16x8 a = aok ? ld8(inb + (long)arow*2048 + kt*32 + kc) : bzero8();
    const __bf16* bp = wp + (((long)kt*128 + nb*16 + cg*4)*64 + ln)*8;
#pragma unroll
    for (int q = 0; q < 4; ++q){
      bf16x8 b = ld8(bp + (long)q*512);
      acc[q] = MFMA(a, b, acc[q]);
    }
  }
  const int r4 = (ln >> 4) << 2;
#pragma unroll
  for (int q = 0; q < 4; ++q){
    int col = (nb*16 + cg*4 + q)*16 + (ln & 15);
#pragma unroll
    for (int r = 0; r < 4; ++r){
      int rowo = m0 + r4 + r;
      if (rowo < M) xp[(long)rowo*2048 + col] = acc[q][r] + bs[col];
    }
  }
}

// ---------------- pyramid recurrence: persistent, weight-stationary ----------------
__global__ __launch_bounds__(256, 1) void pyrRecK(
  const float* __restrict__ WhhF, const float* __restrict__ WhhB,
  const float* __restrict__ xpf, const float* __restrict__ xpb,
  __bf16* __restrict__ hbuf,        // [2dir][2par][4][512] coherent
  __bf16* __restrict__ outb,
  float* __restrict__ outf,
  float* __restrict__ h0f, __bf16* __restrict__ h0b,
  unsigned* __restrict__ slotsF, unsigned* __restrict__ slotsB,
  int T, int isLast)
{
  __shared__ __align__(16) __bf16 WL[128*512];
  __shared__ __align__(16) __bf16 hsL[4*512];
  __shared__ float glds[4][4][32];
  const int tid = threadIdx.x, ln = tid & 63, w = tid >> 6;
  const int bk = blockIdx.x;
  const int dir = bk >> 4, blk = bk & 15;
  const int hc0 = blk * 32;
  const float* Whh = dir ? WhhB : WhhF;
  const float* xp  = dir ? xpb : xpf;
  unsigned* slots = dir ? slotsB : slotsF;

  for (int it = 0; it < 32; ++it){
    int g = it*256 + tid;
    int rho = g >> 6, c8 = g & 63;
    int gate = rho >> 5, hcl = rho & 31;
    const float* src = Whh + ((long)(gate*512 + hc0 + hcl))*512 + c8*8;
    bf16x8 v;
#pragma unroll
    for (int j=0;j<8;++j) v[j] = (__bf16)src[j];
    int off = (rho*1024 + c8*16) ^ ((rho & 7) << 4);
    st8((__bf16*)((char*)WL + off), v);
  }
  if (tid < 64){
    int b = tid >> 4, j = tid & 15;
    ast((unsigned*)hbuf + (((dir*2 + 0)*4 + b)*512 + hc0 + j*2)/2, 0u);
  }
  unsigned ep = 1;
  flagbar(slots, 16, blk, ep++);

  float cv = 0.0f;
  const int arow = ln & 15;
  const int kc = (ln >> 4) << 3;
  const int rho0 = w*32 + (ln & 15);
  const int rho1 = rho0 + 16;
  for (int t = 0; t < T; ++t){
    int par = t & 1;
    int pos = dir ? (T-1-t) : t;
    // copy h (4x512 bf16) coherently -> LDS
    { const unsigned* hq = (const unsigned*)(hbuf + (size_t)(dir*2 + par)*4*512);
      unsigned* hl = (unsigned*)hsL;
#pragma unroll
      for (int i=0;i<4;++i) hl[tid*4+i] = ald(hq + tid*4+i);
    }
    __syncthreads();
    f32x4 a0 = {0.f,0.f,0.f,0.f}, a1 = {0.f,0.f,0.f,0.f};
    for (int kt = 0; kt < 16; ++kt){
      bf16x8 a = (arow < 4) ? ld8(hsL + arow*512 + kt*32 + kc) : bzero8();
      int k2 = (kt*32 + kc)*2;
      bf16x8 b0 = ld8((__bf16*)((char*)WL + ((rho0*1024 + k2) ^ ((rho0 & 7) << 4))));
      bf16x8 b1 = ld8((__bf16*)((char*)WL + ((rho1*1024 + k2) ^ ((rho1 & 7) << 4))));
      a0 = MFMA(a, b0, a0);
      a1 = MFMA(a, b1, a1);
    }
    if (ln < 16){
#pragma unroll
      for (int r=0;r<4;++r){ glds[w][r][ln] = a0[r]; glds[w][r][16+ln] = a1[r]; }
    }
    __syncthreads();
    if (tid < 128){
      int b = tid >> 5, hcl = tid & 31, hcg = hc0 + hcl;
      const float* xr = xp + ((long)(b*T + pos))*2048;
      float ig = glds[0][b][hcl] + xr[hcg];
      float fg = glds[1][b][hcl] + xr[512 + hcg];
      float gg = glds[2][b][hcl] + xr[1024 + hcg];
      float og = glds[3][b][hcl] + xr[1536 + hcg];
      cv = sigf(fg)*cv + sigf(ig)*tanhf(gg);
      float h = sigf(og)*tanhf(cv);
      float hn = __shfl_down(h, 1);
      if (!(hcl & 1))
        ast((unsigned*)hbuf + (((dir*2 + (par^1))*4 + b)*512 + hcg)/2, packbf(h, hn));
      if (!isLast){
        outb[((long)(b*T + pos))*1024 + dir*512 + hcg] = (__bf16)h;
      } else {
        outf[((long)(b*T + pos))*1024 + dir*512 + hcg] = h;
        if (t == T-1){
          h0f[b*1024 + dir*512 + hcg] = h;
          h0b[b*1024 + dir*512 + hcg] = (__bf16)h;
        }
      }
    }
    flagbar(slots, 16, blk, ep++);
  }
}

// ---------------- decoder: persistent, 64 blocks, 3 flag-barriers/step ----------------
__global__ __launch_bounds__(256, 1) void decoderK(
  const float* __restrict__ gWih,
  const float* __restrict__ gWhh,
  const float* __restrict__ gbih, const float* __restrict__ gbhh,
  const float* __restrict__ combBias, const float* __restrict__ attnBias,
  const float* __restrict__ outW, const float* __restrict__ outBias,
  const __bf16* __restrict__ attnP, const __bf16* __restrict__ combP,
  const float* __restrict__ encOut,  // [4][30][1024] f32 (read-only, L2-cached)
  float* __restrict__ HF,            // [2][4][1024] coherent
  __bf16* __restrict__ HB,           // [2][4][1024] coherent
  __bf16* __restrict__ XB,           // [4][512] coherent
  __bf16* __restrict__ CTXB,         // [4][1024] coherent
  float* __restrict__ dout,
  unsigned* __restrict__ slots)
{
  __shared__ __align__(16) __bf16 WgiL[48*512];
  __shared__ __align__(16) __bf16 WghL[48*1024];
  __shared__ __align__(16) __bf16 hL[4*1024];
  __shared__ __bf16 encOutL[4][30][16];
  __shared__ __align__(16) __bf16 inpL[32];
  __shared__ float awL[4][30];
  __shared__ float redL[4][8];
  __shared__ float ghL[3][4][16];
  __shared__ float rzL[2][4][16];
  __shared__ float inL[4][16], hnL[4][16];

  const int tid = threadIdx.x, ln = tid & 63, w = tid >> 6;
  const int bk = blockIdx.x;
  const int hc0 = bk * 16;

  for (int it = 0; it < 12; ++it){
    int g = it*256 + tid;
    int rho = g >> 6, c8 = g & 63;
    int gate = rho >> 4, r16 = rho & 15;
    const float* s = gWih + ((long)(gate*1024 + hc0 + r16))*512 + c8*8;
    bf16x8 v;
#pragma unroll
    for (int j=0;j<8;++j) v[j] = (__bf16)s[j];
    st8((__bf16*)((char*)WgiL + ((rho*1024 + c8*16) ^ ((rho & 7) << 4))), v);
  }
  for (int it = 0; it < 24; ++it){
    int g = it*256 + tid;
    int rho = g >> 7, c8 = g & 127;
    int gate = rho >> 4, r16 = rho & 15;
    const float* s = gWhh + ((long)(gate*1024 + hc0 + r16))*1024 + c8*8;
    bf16x8 v;
#pragma unroll
    for (int j=0;j<8;++j) v[j] = (__bf16)s[j];
    st8((__bf16*)((char*)WghL + ((rho*2048 + c8*16) ^ ((rho & 7) << 4))), v);
  }
  for (int idx = tid; idx < 1920; idx += 256){
    int b = idx/480, rem = idx%480;
    int t2 = rem >> 4, dl = rem & 15;
    encOutL[b][t2][dl] = (__bf16)encOut[((long)b*30 + t2)*1024 + hc0 + dl];
  }
  __syncthreads();

  unsigned ep = 1;
  for (int s = 0; s <= 32; ++s){
    int par = s & 1;
    if (s > 0) flagbar(slots, 64, bk, ep++);
    // copy h[par] (4x1024 bf16) -> LDS
    { const unsigned* hq = (const unsigned*)(HB + (size_t)par*4096);
      unsigned* hl = (unsigned*)hL;
#pragma unroll
      for (int i=0;i<8;++i) hl[tid*8+i] = ald(hq + tid*8+i);
    }
    __syncthreads();
    if (s == 0){
      if (tid < 32) inpL[tid] = (__bf16)0.0f;
      __syncthreads();
    } else {
      int o = tid >> 3, sl = tid & 7;
      int b = o >> 3, l = o & 7;
      const unsigned* hl = (const unsigned*)hL + b*512 + sl*64;
      const float* wrow = outW + l*1024;
      float p = 0.f;
      for (int kk = 0; kk < 64; ++kk){
        int kk2 = (kk + sl*8) & 63;
        unsigned u = hl[kk2];
        p += bflo(u)*wrow[sl*128 + kk2*2] + bfhi(u)*wrow[sl*128 + kk2*2 + 1];
      }
      p += __shfl_down(p, 4);
      p += __shfl_down(p, 2);
      p += __shfl_down(p, 1);
      if (sl == 0) redL[b][l] = p + outBias[l];
      __syncthreads();
      if (tid < 4){
        float m = redL[tid][0];
        for (int l2=1;l2<8;++l2) m = fmaxf(m, redL[tid][l2]);
        float sum = 0.f;
        for (int l2=0;l2<8;++l2) sum += __expf(redL[tid][l2]-m);
        float lse = m + __logf(sum);
        for (int l2=0;l2<8;++l2){
          float lp = redL[tid][l2] - lse;
          inpL[tid*8 + l2] = (__bf16)lp;
          if (bk == 0) dout[((long)tid*32 + (s-1))*8 + l2] = lp;
        }
      }
      __syncthreads();
    }
    if (s == 32) break;

    // P1: wave0 attn logits; waves1-3 gh gates  (A from LDS hL/inpL)
    if (w == 0){
      for (int nt = 0; nt < 2; ++nt){
        f32x4 acc = {0.f,0.f,0.f,0.f};
        for (int kt = 0; kt < 33; ++kt){
          int k = kt*32 + ((ln >> 4) << 3);
          int row = ln & 15;
          bf16x8 a;
          if (row >= 4) a = bzero8();
          else if (k == 0) a = ld8(inpL + row*8);
          else { int off = k - 8; a = (off < 1024) ? ld8(hL + row*1024 + off) : bzero8(); }
          bf16x8 b = ld8(attnP + (((long)kt*2 + nt)*64 + ln)*8);
          acc = MFMA(a, b, acc);
        }
        if (ln < 16 && nt*16 + ln < 30){
          int col = nt*16 + ln;
#pragma unroll
          for (int r=0;r<4;++r) awL[r][col] = acc[r] + attnBias[col];
        }
      }
    } else {
      int gate = w - 1;
      f32x4 acc = {0.f,0.f,0.f,0.f};
      for (int kt = 0; kt < 32; ++kt){
        int row = ln & 15;
        int k = kt*32 + ((ln >> 4) << 3);
        bf16x8 a = (row < 4) ? ld8(hL + row*1024 + k) : bzero8();
        int rho = gate*16 + row;
        bf16x8 b = ld8((__bf16*)((char*)WghL + ((rho*2048 + k*2) ^ ((rho & 7) << 4))));
        acc = MFMA(a, b, acc);
      }
      if (ln < 16){
#pragma unroll
        for (int r=0;r<4;++r) ghL[gate][r][ln] = acc[r];
      }
    }
    __syncthreads();
    if (tid < 4){
      float m = awL[tid][0];
      for (int t2=1;t2<30;++t2) m = fmaxf(m, awL[tid][t2]);
      float sum = 0.f;
      for (int t2=0;t2<30;++t2){ float e = __expf(awL[tid][t2]-m); awL[tid][t2] = e; sum += e; }
      float inv = 1.0f/sum;
      for (int t2=0;t2<30;++t2) awL[tid][t2] *= inv;
    }
    __syncthreads();
    // ctxv slice (16 d-cols per block) from LDS-cached encOut
    if (tid < 64){
      int b = tid >> 4, dl = tid & 15;
      float sum = 0.f;
      for (int t2=0;t2<30;++t2) sum += awL[b][t2]*(float)encOutL[b][t2][dl];
      float sn = __shfl_down(sum, 1);
      if (!(dl & 1))
        ast((unsigned*)CTXB + (b*1024 + hc0 + dl)/2, packbf(sum, sn));
    }
    flagbar(slots, 64, bk, ep++);

    // P2: comb slices (blocks 0..31, wave0)
    if (w == 0 && bk < 32){
      f32x4 acc = {0.f,0.f,0.f,0.f};
      for (int kt = 0; kt < 33; ++kt){
        int k = kt*32 + ((ln >> 4) << 3);
        int row = ln & 15;
        bf16x8 a;
        if (row >= 4) a = bzero8();
        else if (k == 0) a = ld8(inpL + row*8);
        else { int off = k - 8; a = (off < 1024) ? ald8(CTXB + row*1024 + off) : bzero8(); }
        bf16x8 b = ld8(combP + (((long)kt*32 + bk)*64 + ln)*8);
        acc = MFMA(a, b, acc);
      }
      if (ln < 16){
        int col = bk*16 + ln;
#pragma unroll
        for (int r=0;r<4;++r){
          float x = fmaxf(acc[r] + combBias[col], 0.0f);
          float xn = __shfl_down(x, 1);
          if (!(ln & 1))
            ast((unsigned*)XB + (r*512 + col)/2, packbf(x, xn));
        }
      }
    }
    flagbar(slots, 64, bk, ep++);

    // P3: gi gates + GRU cell
    if (w < 3){
      int gate = w;
      f32x4 acc = {0.f,0.f,0.f,0.f};
      for (int kt = 0; kt < 16; ++kt){
        int row = ln & 15;
        int k = kt*32 + ((ln >> 4) << 3);
        bf16x8 a = (row < 4) ? ald8(XB + row*512 + k) : bzero8();
        int rho = gate*16 + row;
        bf16x8 b = ld8((__bf16*)((char*)WgiL + ((rho*1024 + k*2) ^ ((rho & 7) << 4))));
        acc = MFMA(a, b, acc);
      }
      if (ln < 16){
        int hcg = hc0 + ln;
        float bi = gbih[gate*1024 + hcg];
        float bh = gbhh[gate*1024 + hcg];
#pragma unroll
        for (int r=0;r<4;++r){
          float gi_v = acc[r] + bi;
          float gh_v = ghL[gate][r][ln] + bh;
          if (gate == 0) rzL[0][r][ln] = sigf(gi_v + gh_v);
          else if (gate == 1) rzL[1][r][ln] = sigf(gi_v + gh_v);
          else { inL[r][ln] = gi_v; hnL[r][ln] = gh_v; }
        }
      }
    }
    __syncthreads();
    if (tid < 64){
      int b = tid >> 4, l = tid & 15;
      int hcg = hc0 + l;
      float n = tanhf(inL[b][l] + rzL[0][b][l]*hnL[b][l]);
      float z = rzL[1][b][l];
      float hold = aldf(HF + ((size_t)par*4 + b)*1024 + hcg);
      float hnew = (1.0f - z)*n + z*hold;
      astf(HF + ((size_t)(par^1)*4 + b)*1024 + hcg, hnew);
      float h2 = __shfl_down(hnew, 1);
      if (!(l & 1))
        ast((unsigned*)HB + (((par^1)*4 + b)*1024 + hcg)/2, packbf(hnew, h2));
    }
  }
}

// ---------------- host ----------------
static const size_t O_BAR   = 0;          // 12288 (12 groups worth: 8 pyr (1KB) + 4KB dec)
static const size_t O_XSB   = 12288;
static const size_t O_WCATP = 1487872;
static const size_t O_BIASC = 3716096;
static const size_t O_HENC  = 3725312;
static const size_t O_CENC  = 5692416;
static const size_t O_CTX   = 9625600;
static const size_t O_WIHPF = 13558784;
static const size_t O_WIHPB = 21948416;
static const size_t O_BSUM  = 30338048;
static const size_t O_XPF   = 30355456;
static const size_t O_XPB   = 38220800;
static const size_t O_HPYR  = 46086144;
static const size_t O_OUTA  = 46103552;
static const size_t O_OUTB  = 48070656;
static const size_t O_ENCO  = 49054720;
static const size_t O_HF    = 49547264;
static const size_t O_HB    = 49581056;
static const size_t O_ATTNP = 49598464;
static const size_t O_COMBP = 49667072;
static const size_t O_XBF   = 50749440;
static const size_t O_CTXB  = 50754560;
// end ~50762752 (~48.4 MiB)

extern "C" void kernel_launch(void* const* d_in, const int* in_sizes, int n_in,
                              void* d_out, int out_size, void* d_ws, size_t ws_size,
                              hipStream_t stream)
{
  const float* xs    = (const float*)d_in[0];
  const int*   xlen  = (const int*)d_in[1];
  const float* eWih  = (const float*)d_in[2];
  const float* eWhh  = (const float*)d_in[3];
  const float* ebih  = (const float*)d_in[4];
  const float* ebhh  = (const float*)d_in[5];
  const float* pWihF = (const float*)d_in[6];
  const float* pWhhF = (const float*)d_in[7];
  const float* pbihF = (const float*)d_in[8];
  const float* pbhhF = (const float*)d_in[9];
  const float* pWihB = (const float*)d_in[10];
  const float* pWhhB = (const float*)d_in[11];
  const float* pbihB = (const float*)d_in[12];
  const float* pbhhB = (const float*)d_in[13];
  const float* attnW = (const float*)d_in[14];
  const float* attnb = (const float*)d_in[15];
  const float* combW = (const float*)d_in[16];
  const float* combb = (const float*)d_in[17];
  const float* gWih  = (const float*)d_in[18];
  const float* gWhh  = (const float*)d_in[19];
  const float* gbih  = (const float*)d_in[20];
  const float* gbhh  = (const float*)d_in[21];
  const float* outW  = (const float*)d_in[22];
  const float* outb  = (const float*)d_in[23];

  char* ws = (char*)d_ws;
  unsigned* BARU  = (unsigned*)(ws + O_BAR);
  __bf16* XSB     = (__bf16*)(ws + O_XSB);
  __bf16* WCATP   = (__bf16*)(ws + O_WCATP);
  float*  BIASC   = (float*)(ws + O_BIASC);
  __bf16* HENC    = (__bf16*)(ws + O_HENC);
  float*  CENC    = (float*)(ws + O_CENC);
  __bf16* CTX     = (__bf16*)(ws + O_CTX);
  __bf16* WIHPF   = (__bf16*)(ws + O_WIHPF);
  __bf16* WIHPB   = (__bf16*)(ws + O_WIHPB);
  float*  BSUM    = (float*)(ws + O_BSUM);
  float*  XPF     = (float*)(ws + O_XPF);
  float*  XPB     = (float*)(ws + O_XPB);
  __bf16* HPYR    = (__bf16*)(ws + O_HPYR);
  __bf16* OUTA    = (__bf16*)(ws + O_OUTA);
  __bf16* OUTB    = (__bf16*)(ws + O_OUTB);
  float*  ENCO    = (float*)(ws + O_ENCO);
  float*  HF      = (float*)(ws + O_HF);
  __bf16* HB      = (__bf16*)(ws + O_HB);
  __bf16* ATTNP   = (__bf16*)(ws + O_ATTNP);
  __bf16* COMBP   = (__bf16*)(ws + O_COMBP);
  __bf16* XBF     = (__bf16*)(ws + O_XBF);
  __bf16* CTXB    = (__bf16*)(ws + O_CTXB);

  zeroBarK<<<1, 256, 0, stream>>>(BARU);
  packSmallK<<<1193, 256, 0, stream>>>(xs, eWih, eWhh, ebih, ebhh, attnW, combW,
      XSB, WCATP, BIASC, ATTNP, COMBP);

  for (int t = 0; t < 12; ++t)
    encStepK<<<dim3(30, 8), 256, 0, stream>>>(XSB, HENC, CENC, WCATP, BIASC, xlen, CTX, t);

  const int Ts[4] = {240, 120, 60, 30};
  const __bf16* ins[4] = {CTX, OUTA, OUTB, OUTA};
  __bf16* outs[4] = {OUTA, OUTB, OUTA, OUTB};
  for (int L = 0; L < 4; ++L){
    int T = Ts[L];
    packPencK<<<4113, 256, 0, stream>>>(pWihF + (long)L*2048*2048, pWihB + (long)L*2048*2048,
        pbihF + L*2048, pbhhF + L*2048, pbihB + L*2048, pbhhB + L*2048,
        WIHPF, WIHPB, BSUM);
    int MB = (4*T + 63)/64;
    pencInK<<<dim3(MB, 8, 2), 1024, 0, stream>>>(ins[L], WIHPF, WIHPB, BSUM, XPF, XPB, 4*T);
    pyrRecK<<<32, 256, 0, stream>>>(pWhhF + (long)L*2048*512, pWhhB + (long)L*2048*512,
        XPF, XPB, HPYR, outs[L], ENCO, HF, HB,
        BARU + (size_t)(L*2+0)*256, BARU + (size_t)(L*2+1)*256, T, (L==3) ? 1 : 0);
  }

  decoderK<<<64, 256, 0, stream>>>(gWih, gWhh, gbih, gbhh, combb, attnb, outW, outb,
      ATTNP, COMBP, ENCO, HF, HB, XBF, CTXB, (float*)d_out,
      BARU + 2048);
}